// Round 11
// baseline (267.017 us; speedup 1.0000x reference)
//
#include <hip/hip_runtime.h>
#include <hip/hip_bf16.h>

#define D_MODEL 1024
#define NH 16
#define DK 64
#define S_LEN 2048
#define BATCH 2
#define M_ROWS (BATCH * S_LEN)   // 4096

typedef float    floatx4 __attribute__((ext_vector_type(4)));
typedef _Float16 half8   __attribute__((ext_vector_type(8)));
typedef _Float16 half4v  __attribute__((ext_vector_type(4)));

#define LOG2E 1.4426950408889634f
#define EXPM1 0.36787944117144233f   // exp(-1) = exp2(-LOG2E)

__device__ __forceinline__ half8 ldh8(const _Float16* p) {
    return __builtin_bit_cast(half8, *(const uint4*)p);
}
__device__ __forceinline__ void gld16(const void* g, void* l) {
    __builtin_amdgcn_global_load_lds(
        (const __attribute__((address_space(1))) void*)g,
        (__attribute__((address_space(3))) void*)l, 16, 0, 0);
}
// swap lanes 0<->1, 2<->3 within each quad (DPP quad_perm(1,0,3,2))
__device__ __forceinline__ float dpp_swap1(float x) {
    return __builtin_bit_cast(float,
        __builtin_amdgcn_mov_dpp(__builtin_bit_cast(int, x), 0xB1, 0xF, 0xF, false));
}
// raw workgroup barrier without the __syncthreads() vmcnt(0) drain
__device__ __forceinline__ void rawbar() {
    __builtin_amdgcn_sched_barrier(0);
    __builtin_amdgcn_s_barrier();
    __builtin_amdgcn_sched_barrier(0);
}

// ---------------------------------------------------------------------------
// prep: fused fp32->fp16 casts (q,k,v,wq,wk,wv,wo) + mask bit-pack.
// grid (4096, 8), 256 thr.  y 0-2: qkv rows (R=4096); y 3-6: weights
// (R=1024, blocks >=1024 idle); y 7: mask_pack (16 words/block).
// ---------------------------------------------------------------------------
__global__ __launch_bounds__(256)
void prep(const float* __restrict__ q, const float* __restrict__ k,
          const float* __restrict__ v, const float* __restrict__ wq,
          const float* __restrict__ wk, const float* __restrict__ wv,
          const float* __restrict__ wo, const int* __restrict__ mask,
          _Float16* __restrict__ Ah, _Float16* __restrict__ Wh,
          unsigned long long* __restrict__ mb) {
    const int y = blockIdx.y;
    if (y < 7) {
        if (y >= 3 && blockIdx.x >= 1024) return;   // weights: R=1024
        const float* src = (y == 0) ? q : (y == 1) ? k : (y == 2) ? v :
                           (y == 3) ? wq : (y == 4) ? wk : (y == 5) ? wv : wo;
        _Float16* dst = (y < 3) ? (Ah + (size_t)y * M_ROWS * 1024)
                                : (Wh + (size_t)(y - 3) * 1024 * 1024);
        const size_t idx = ((size_t)blockIdx.x * 256 + threadIdx.x) * 4;
        float4 f = *(const float4*)&src[idx];
        half4v h = {(_Float16)f.x, (_Float16)f.y, (_Float16)f.z, (_Float16)f.w};
        *(half4v*)&dst[idx] = h;
    } else {
        const int wv_ = threadIdx.x >> 6, lane = threadIdx.x & 63;
#pragma unroll
        for (int i = 0; i < 4; i++) {
            const int gw = blockIdx.x * 16 + wv_ * 4 + i;
            const int row = gw >> 5, wid = gw & 31;
            const int mv = mask[(size_t)row * S_LEN + wid * 64 + lane];
            unsigned long long bal = __ballot(mv != 0);
            if (lane == 0) mb[gw] = bal;
        }
    }
}

// ---------------------------------------------------------------------------
// C = A[M,1024] @ W[1024,1024]^T (+bias), fp16 MFMA.  Tile 128m x 64n +
// chunked XCD swizzle = round-9's tile (more blocks/CU: gemm<1> 3->up to 6,
// gemm<0> 1->2) with its re-read amplification neutralized by round-10's
// VALIDATED chunking (each XCD owns 4m x 4n super-tiles of 16 blocks;
// working set 4 A panels + 4 W bands = 1.5 MB < 4 MB L2, both operands
// XCD-local).  Round 9 tested the tile w/o swizzle (-10.6 us); round 10
// the swizzle w/o tile (+7 us); this is the untested combination.
// Bijective decode: id -> xcd=id&7, slot=id>>3, chunk=slot>>4, t=slot&15;
// g=chunk*8+xcd; z=g>>5; cz=g&31; mi=(cz&7)*4+(t>>2); ni=(cz>>3)*4+(t&3).
// K-loop (validated round 6, issue-early/gate-late): vmcnt(0)+rawbar gate
// -> ds_read frags -> lgkmcnt(0)+rawbar -> issue tile k+1 -> MFMAs.
// 4 waves as 2m x 2n; per wave 64m x 32n, acc[4][2] (32 VGPR; ~90 total,
// bounds(256,4) pins the 128 cap -> 4 blocks/CU resident).
// OUTMODE 0: fp32 row-major out.  OUTMODE 1: fp16 head-major via
// LDS-staged coalesced epilogue; z==0 (Q) pre-scaled; z==2 (V) staged
// transposed -> lands directly in Vt [bh][d][s]; one head per n-tile.
// ---------------------------------------------------------------------------
template <int OUTMODE>
__global__ __launch_bounds__(256, 4)
void gemm_f16(const _Float16* __restrict__ Abase, const _Float16* __restrict__ Wbase,
              const float* __restrict__ b0, const float* __restrict__ b1,
              const float* __restrict__ b2, void* __restrict__ Obase,
              void* __restrict__ Obase2) {
    __shared__ __align__(16) _Float16 SM[12288];   // As(8K) | Ws(4K) halfs = 24 KB
    _Float16* As = SM;                              // [128][64]
    _Float16* Ws = SM + 8192;                       // [64][64]
    const int tid = threadIdx.x;
    const int w = tid >> 6, lane = tid & 63;
    const int l15 = lane & 15, q4 = lane >> 4;

    // chunked XCD swizzle (hardware xcd = linear_id % 8)
    const int id = blockIdx.x + (blockIdx.y << 4) +
                   ((OUTMODE == 1) ? ((int)blockIdx.z << 9) : 0);
    const int xcd = id & 7, slot = id >> 3;
    const int chunk = slot >> 4, t = slot & 15;
    const int g = chunk * 8 + xcd;          // global chunk index
    const int z = (OUTMODE == 1) ? (g >> 5) : 0;
    const int cz = g & 31;                  // chunk within z: 8 m-chunks x 4 n-chunks
    const int mi = (cz & 7) * 4 + (t >> 2);
    const int ni = (cz >> 3) * 4 + (t & 3);
    const int m0 = mi * 128, n0 = ni * 64;
    const int wm = w >> 1, wn = w & 1;

    const _Float16* A = Abase + (size_t)z * M_ROWS * 1024;
    const _Float16* W = Wbase + (size_t)z * 1024 * 1024;
    const float* bias = (OUTMODE == 1) ? ((z == 0) ? b0 : (z == 1) ? b1 : b2) : b0;

    // staging slots: A 4/thread (rows 0..127), W 2/thread (rows 0..63)
    int srow[4], sseg[4];
#pragma unroll
    for (int i = 0; i < 4; i++) {
        const int s2 = i * 256 + tid;
        srow[i] = s2 >> 3;
        sseg[i] = ((s2 & 7) ^ (srow[i] & 7)) * 8;
    }

    int aoff[4][2], woff[2][2];
#pragma unroll
    for (int r = 0; r < 4; r++) {
        const int ar = wm * 64 + r * 16 + l15;
#pragma unroll
        for (int kc = 0; kc < 2; kc++)
            aoff[r][kc] = (ar * 8 + ((kc * 4 + q4) ^ (ar & 7))) * 8;
    }
#pragma unroll
    for (int c = 0; c < 2; c++) {
        const int wr = wn * 32 + c * 16 + l15;
#pragma unroll
        for (int kc = 0; kc < 2; kc++)
            woff[c][kc] = (wr * 8 + ((kc * 4 + q4) ^ (wr & 7))) * 8;
    }

    floatx4 acc[4][2];
#pragma unroll
    for (int r = 0; r < 4; r++)
#pragma unroll
        for (int c = 0; c < 2; c++) acc[r][c] = (floatx4){0.f, 0.f, 0.f, 0.f};

    // prologue: stage tile k0=0   (A: 4 gld16, W: 2 gld16)
#pragma unroll
    for (int i = 0; i < 4; i++)
        gld16(&A[(size_t)(m0 + srow[i]) * 1024 + sseg[i]],
              &As[(i * 256 + w * 64) * 8]);
#pragma unroll
    for (int i = 0; i < 2; i++)
        gld16(&W[(size_t)(n0 + srow[i]) * 1024 + sseg[i]],
              &Ws[(i * 256 + w * 64) * 8]);

    for (int k0 = 0; k0 < 1024; k0 += 64) {
        // gate: tile k0 landed (loads flew over previous MFMA block)
        __builtin_amdgcn_sched_barrier(0);
        asm volatile("s_waitcnt vmcnt(0)" ::: "memory");
        rawbar();

        half8 af[4][2], wf[2][2];
#pragma unroll
        for (int r = 0; r < 4; r++)
#pragma unroll
            for (int kc = 0; kc < 2; kc++)
                af[r][kc] = ldh8(&As[aoff[r][kc]]);
#pragma unroll
        for (int c = 0; c < 2; c++)
#pragma unroll
            for (int kc = 0; kc < 2; kc++)
                wf[c][kc] = ldh8(&Ws[woff[c][kc]]);
        // all waves done reading the LDS tile -> safe to overwrite
        asm volatile("s_waitcnt lgkmcnt(0)" ::: "memory");
        rawbar();

        if (k0 < 1024 - 64) {
#pragma unroll
            for (int i = 0; i < 4; i++)
                gld16(&A[(size_t)(m0 + srow[i]) * 1024 + (k0 + 64) + sseg[i]],
                      &As[(i * 256 + w * 64) * 8]);
#pragma unroll
            for (int i = 0; i < 2; i++)
                gld16(&W[(size_t)(n0 + srow[i]) * 1024 + (k0 + 64) + sseg[i]],
                      &Ws[(i * 256 + w * 64) * 8]);
        }
        __builtin_amdgcn_sched_barrier(0);   // keep stage-issue above the MFMAs

#pragma unroll
        for (int kc = 0; kc < 2; kc++)
#pragma unroll
            for (int r = 0; r < 4; r++)
#pragma unroll
                for (int c = 0; c < 2; c++)
                    acc[r][c] = __builtin_amdgcn_mfma_f32_16x16x32_f16(
                        af[r][kc], wf[c][kc], acc[r][c], 0, 0, 0);
    }

    if (OUTMODE == 0) {
#pragma unroll
        for (int r = 0; r < 4; r++)
#pragma unroll
            for (int c = 0; c < 2; c++) {
                const int n = n0 + wn * 32 + c * 16 + l15;
                const int mbase = m0 + wm * 64 + r * 16 + q4 * 4;
#pragma unroll
                for (int reg = 0; reg < 4; reg++)
                    ((float*)Obase)[(size_t)(mbase + reg) * 1024 + n] =
                        acc[r][c][reg] + bias[n];
            }
    } else {
        const int h0 = n0 >> 6;          // exactly one head per n-tile
        const int bB = m0 >> 11;         // batch (tile never crosses: 2048%128==0)
        if (z == 2) {
            // stage transposed E[n(64)][m(128)] (XOR-swizzled 16-B slots)
#pragma unroll
            for (int r = 0; r < 4; r++)
#pragma unroll
                for (int c = 0; c < 2; c++) {
                    const int nl = wn * 32 + c * 16 + l15;
                    const int ml = wm * 64 + r * 16 + q4 * 4;
                    half4v hv;
#pragma unroll
                    for (int reg = 0; reg < 4; reg++)
                        hv[reg] = (_Float16)(acc[r][c][reg] + bias[n0 + nl]);
                    const int seg = ml >> 3, wi = ml & 7;
                    *(half4v*)&SM[nl * 128 + ((seg ^ (nl & 7)) << 3) + wi] = hv;
                }
            __syncthreads();
#pragma unroll
            for (int it = 0; it < 4; it++) {
                const int c2 = it * 256 + tid;
                const int row = c2 >> 4, seg = c2 & 15;   // row=n(d), seg of m
                half8 v8 = ldh8(&SM[row * 128 + ((seg ^ (row & 7)) << 3)]);
                const int s = (m0 & 2047) + seg * 8;
                *(uint4*)&((_Float16*)Obase2)[
                    (((size_t)((bB * 16 + h0) * 64 + row)) << 11) + s] =
                    __builtin_bit_cast(uint4, v8);
            }
        } else {
            const float sc = (z == 0) ? 0.125f * LOG2E : 1.0f;
            // stage E[m(128)][n(64)] (scalar b16 writes, XOR-swizzled 16-B slots)
#pragma unroll
            for (int r = 0; r < 4; r++)
#pragma unroll
                for (int c = 0; c < 2; c++) {
                    const int nl = wn * 32 + c * 16 + l15;
                    const int seg = nl >> 3, wi = nl & 7;
                    const float bv = bias[n0 + nl];
#pragma unroll
                    for (int reg = 0; reg < 4; reg++) {
                        const int ml = wm * 64 + r * 16 + q4 * 4 + reg;
                        SM[ml * 64 + ((seg ^ (ml & 7)) << 3) + wi] =
                            (_Float16)((acc[r][c][reg] + bv) * sc);
                    }
                }
            __syncthreads();
            _Float16* Oz = (_Float16*)Obase + (size_t)z * M_ROWS * 1024;
#pragma unroll
            for (int it = 0; it < 4; it++) {
                const int c2 = it * 256 + tid;
                const int row = c2 >> 3, seg = c2 & 7;   // row=m, seg of n
                half8 v8 = ldh8(&SM[row * 64 + ((seg ^ (row & 7)) << 3)]);
                const int s = (m0 + row) & 2047;
                *(uint4*)&Oz[(((size_t)(bB * 16 + h0) * S_LEN + s) << 6) + seg * 8] =
                    __builtin_bit_cast(uint4, v8);
            }
        }
    }
}

// ---------------------------------------------------------------------------
// MFMA flash attention v8 (round-6 exact): in-block key-split +
// counted-vmcnt K/V pipeline + setprio.
// Grid (S/128, B*H), 512 thr, LDS 68.9 KB -> 2 blocks/CU = 16 waves/CU.
// ---------------------------------------------------------------------------
__global__ __launch_bounds__(512, 4)
void attn_mfma(const _Float16* __restrict__ Qh, const _Float16* __restrict__ Kh,
               const _Float16* __restrict__ Vt, const unsigned long long* __restrict__ mb,
               _Float16* __restrict__ Xh) {
    __shared__ __align__(16) _Float16 Ks[2][64 * 64];   // [half][key][d]  16 KB
    __shared__ __align__(16) _Float16 Vs[2][64 * 64];   // [half][d][key]  16 KB
    __shared__ __align__(16) _Float16 Ps[8][32 * 72];   // per-wave P, 36.9 KB

    const int tid = threadIdx.x;
    const int w = tid >> 6, lane = tid & 63;
    const int z = w >> 2, w4 = w & 3;       // key-half, wave-within-half
    const int t255 = tid & 255;
    const int l15 = lane & 15, q4 = lane >> 4;
    const int bh = blockIdx.y, b = bh >> 4, h = bh & 15;
    const int qb = blockIdx.x * 128 + w4 * 32;
    const int kbase = z * 1024;

    const _Float16* Qg = Qh + ((size_t)bh * S_LEN + qb) * DK;
    const _Float16* Kg = Kh + ((size_t)bh * S_LEN + kbase) * DK;
    const _Float16* Vg = Vt + (size_t)bh * DK * S_LEN + kbase;

    // Q fragments (A-operand), resident all kernel (scale pre-folded in gemm)
    half8 Aq[2][2];
#pragma unroll
    for (int qs = 0; qs < 2; qs++)
#pragma unroll
        for (int ch = 0; ch < 2; ch++)
            Aq[qs][ch] = ldh8(&Qg[(qs * 16 + l15) * DK + ch * 32 + q4 * 8]);

    // staging slots within each 256-thread half
    int grow[2], gseg[2];
#pragma unroll
    for (int i = 0; i < 2; i++) {
        const int slot = i * 256 + t255;
        grow[i] = slot >> 3;
        gseg[i] = ((slot & 7) ^ (grow[i] & 7)) * 8;
    }

    // fragment base offsets (halfs) into swizzled Ks/Vs; full offset =
    // kb[ch] + jt*1024 (jt*1024 folds into the ds_read immediate)
    int kb[2];
#pragma unroll
    for (int ch = 0; ch < 2; ch++)
        kb[ch] = l15 * 64 + (((ch * 4 + q4) ^ (l15 & 7)) * 8);

    // mask word base: row (qb + q4*4), key-half offset folded in.
    // index per (qs,reg,jw) = qs*512 + reg*32 + jw
    const unsigned long long* mrow_p = mb + (size_t)(qb + q4 * 4) * (S_LEN / 64) + z * 16;

    floatx4 O[2][4];
#pragma unroll
    for (int qs = 0; qs < 2; qs++)
#pragma unroll
        for (int nt = 0; nt < 4; nt++) O[qs][nt] = (floatx4){0.f, 0.f, 0.f, 0.f};
    floatx4 lacc[2];
    lacc[0] = (floatx4){0.f, 0.f, 0.f, 0.f};
    lacc[1] = (floatx4){0.f, 0.f, 0.f, 0.f};

    half8 onesB;
#pragma unroll
    for (int i = 0; i < 8; i++) onesB[i] = (_Float16)1.0f;

    const bool evenlane = ((lane & 1) == 0);

    // prologue: stage K_0 then V_0   (FIFO: K,K,V,V)
#pragma unroll
    for (int i = 0; i < 2; i++) {
        const int lb = (i * 256 + w4 * 64) * 8;
        gld16(&Kg[(size_t)grow[i] * DK + gseg[i]], &Ks[z][lb]);
    }
#pragma unroll
    for (int i = 0; i < 2; i++) {
        const int lb = (i * 256 + w4 * 64) * 8;
        gld16(&Vg[(size_t)grow[i] * S_LEN + gseg[i]], &Vs[z][lb]);
    }

    for (int j0 = 0; j0 < 1024; j0 += 64) {
        const int jn = (j0 + 64) & 1023;   // wrap keeps vmcnt schedule uniform
        const int jw = j0 >> 6;

        // ---- K gate: my K_j landed (V_j may still fly); then block-wide ----
        __builtin_amdgcn_sched_barrier(0);
        asm volatile("s_waitcnt vmcnt(2)" ::: "memory");
        rawbar();

        // ---- QK + fused softmax (per-jt: only one floatx4 live) ----
#pragma unroll
        for (int qs = 0; qs < 2; qs++) {
            unsigned long long mw[4];
#pragma unroll
            for (int jt = 0; jt < 4; jt++) {
                floatx4 c = (floatx4){0.f, 0.f, 0.f, 0.f};
                __builtin_amdgcn_s_setprio(1);
                c = __builtin_amdgcn_mfma_f32_16x16x32_f16(
                    Aq[qs][0], ldh8(&Ks[z][jt * 1024 + kb[0]]), c, 0, 0, 0);
                c = __builtin_amdgcn_mfma_f32_16x16x32_f16(
                    Aq[qs][1], ldh8(&Ks[z][jt * 1024 + kb[1]]), c, 0, 0, 0);
                __builtin_amdgcn_s_setprio(0);
                if (jt == 0) {
#pragma unroll
                    for (int reg = 0; reg < 4; reg++)
                        mw[reg] = mrow_p[qs * 512 + reg * 32 + jw];
                }
#pragma unroll
                for (int reg = 0; reg < 4; reg++) {
                    const unsigned ttw =
                        (unsigned)(mw[reg] >> (jt >= 2 ? 32 : 0)) >> l15;
                    const unsigned sel = ttw & (1u << ((jt & 1) * 16));
                    float p = __builtin_amdgcn_exp2f(c[reg]);
                    p = sel ? p : EXPM1;
                    const float po = dpp_swap1(p);
                    if (evenlane) {
                        *(unsigned*)&Ps[w][(qs * 16 + q4 * 4 + reg) * 72 +
                                           jt * 16 + l15] =
                            __builtin_bit_cast(unsigned,
                                __builtin_amdgcn_cvt_pkrtz(p, po));
                    }
                }
            }
        }

        // ---- Ks consumed block-wide -> prefetch K_{j+1} (flies over PV) ----
        rawbar();
#pragma unroll
        for (int i = 0; i < 2; i++) {
            const int lb = (i * 256 + w4 * 64) * 8;
            gld16(&Kg[(size_t)(jn + grow[i]) * DK + gseg[i]], &Ks[z][lb]);
        }

        // ---- V gate: my V_j landed (K_{j+1} in flight); block-wide ----
        __builtin_amdgcn_sched_barrier(0);
        asm volatile("s_waitcnt vmcnt(2)" ::: "memory");
        rawbar();

        // ---- PV: O[qs] += P[qs] @ V ; Σp via all-ones B ----
#pragma unroll
        for (int qs = 0; qs < 2; qs++) {
            half8 Ap[2];
#pragma unroll
            for (int ch = 0; ch < 2; ch++)
                Ap[ch] = ldh8(&Ps[w][(qs * 16 + l15) * 72 + ch * 32 + q4 * 8]);
            __builtin_amdgcn_s_setprio(1);
            lacc[qs] = __builtin_amdgcn_mfma_f32_16x16x32_f16(Ap[0], onesB, lacc[qs], 0, 0, 0);
            lacc[qs] = __builtin_amdgcn_mfma_f32_16x16x32_f16(Ap[1], onesB, lacc[qs], 0, 0, 0);
#pragma unroll
            for (int nt = 0; nt < 4; nt++) {
                O[qs][nt] = __builtin_amdgcn_mfma_f32_16x16x32_f16(
                    Ap[0], ldh8(&Vs[z][nt * 1024 + kb[0]]), O[qs][nt], 0, 0, 0);
                O[qs][nt] = __builtin_amdgcn_mfma_f32_16x16x32_f16(
                    Ap[1], ldh8(&Vs[z][nt * 1024 + kb[1]]), O[qs][nt], 0, 0, 0);
            }
            __builtin_amdgcn_s_setprio(0);
        }

        // ---- Vs consumed block-wide -> prefetch V_{j+1} (flies over QK) ----
        rawbar();
#pragma unroll
        for (int i = 0; i < 2; i++) {
            const int lb = (i * 256 + w4 * 64) * 8;
            gld16(&Vg[(size_t)grow[i] * S_LEN + jn + gseg[i]], &Vs[z][lb]);
        }
    }
    __builtin_amdgcn_sched_barrier(0);

    // cross-half combine via LDS (reuse Ps region: all P reads are done;
    // the loop's final rawbar ordered the last PV reads before these writes)
    float* Obuf = (float*)&Ps[0][0];                  // [4][32][65] fp32, 33.3 KB
    if (z == 1) {
#pragma unroll
        for (int qs = 0; qs < 2; qs++)
#pragma unroll
            for (int reg = 0; reg < 4; reg++) {
                const int rl = w4 * 32 + qs * 16 + q4 * 4 + reg;
#pragma unroll
                for (int nt = 0; nt < 4; nt++)
                    Obuf[rl * 65 + nt * 16 + l15] = O[qs][nt][reg];
                if (l15 == 0) Obuf[rl * 65 + 64] = lacc[qs][reg];
            }
    }
    __syncthreads();
    if (z == 0) {
#pragma unroll
        for (int qs = 0; qs < 2; qs++)
#pragma unroll
            for (int reg = 0; reg < 4; reg++) {
                const int rl = w4 * 32 + qs * 16 + q4 * 4 + reg;
                const float inv = 1.0f / (lacc[qs][reg] + Obuf[rl * 65 + 64]);
                const int srow = qb + qs * 16 + q4 * 4 + reg;
                _Float16* Xrow = Xh + (size_t)(b * S_LEN + srow) * 1024 + h * DK;
#pragma unroll
                for (int nt = 0; nt < 4; nt++)
                    Xrow[nt * 16 + l15] =
                        (_Float16)((O[qs][nt][reg] + Obuf[rl * 65 + nt * 16 + l15]) * inv);
            }
    }
}

// ---------------------------------------------------------------------------
extern "C" void kernel_launch(void* const* d_in, const int* in_sizes, int n_in,
                              void* d_out, int out_size, void* d_ws, size_t ws_size,
                              hipStream_t stream) {
    const float* q  = (const float*)d_in[0];
    const float* k  = (const float*)d_in[1];
    const float* v  = (const float*)d_in[2];
    const int* mask = (const int*)d_in[3];
    const float* wq = (const float*)d_in[4];
    const float* bq = (const float*)d_in[5];
    const float* wk = (const float*)d_in[6];
    const float* bk = (const float*)d_in[7];
    const float* wv = (const float*)d_in[8];
    const float* bv = (const float*)d_in[9];
    const float* wo = (const float*)d_in[10];
    const float* bo = (const float*)d_in[11];
    float* out = (float*)d_out;

    char* ws = (char*)d_ws;
    const size_t MB = 1u << 20;
    _Float16* Wh   = (_Float16*)ws;                    // 4 x 2 MB (wq,wk,wv,wo)
    _Float16* Ah   = (_Float16*)(ws + 8 * MB);         // 3 x 8 MB (q,k,v fp16)
    _Float16* QKVh = (_Float16*)(ws + 32 * MB);        // 2 x 8 MB head-major (Q,K)
    _Float16* Vt   = (_Float16*)(ws + 56 * MB);        // 8 MB
    unsigned long long* mb = (unsigned long long*)(ws + 64 * MB);  // 512 KB
    _Float16* Xh   = Ah;                               // reuse q slot (8 MB)

    prep<<<dim3(4096, 8), 256, 0, stream>>>(q, k, v, wq, wk, wv, wo, mask,
                                            Ah, Wh, mb);

    gemm_f16<1><<<dim3(16, 32, 3), 256, 0, stream>>>(Ah, Wh, bq, bk, bv, QKVh, Vt);

    attn_mfma<<<dim3(16, 32), 512, 0, stream>>>(QKVh, QKVh + (size_t)M_ROWS * 1024,
                                                Vt, mb, Xh);

    gemm_f16<0><<<dim3(16, 32), 256, 0, stream>>>(Xh, Wh + (size_t)3 * 1024 * 1024,
                                                  bo, bo, bo, out, nullptr);
}

// Round 12
// 248.618 us; speedup vs baseline: 1.0740x; 1.0740x over previous
//
#include <hip/hip_runtime.h>
#include <hip/hip_bf16.h>

#define D_MODEL 1024
#define NH 16
#define DK 64
#define S_LEN 2048
#define BATCH 2
#define M_ROWS (BATCH * S_LEN)   // 4096

typedef float    floatx4 __attribute__((ext_vector_type(4)));
typedef _Float16 half8   __attribute__((ext_vector_type(8)));
typedef _Float16 half4v  __attribute__((ext_vector_type(4)));

#define LOG2E 1.4426950408889634f
#define EXPM1 0.36787944117144233f   // exp(-1) = exp2(-LOG2E)

__device__ __forceinline__ half8 ldh8(const _Float16* p) {
    return __builtin_bit_cast(half8, *(const uint4*)p);
}
__device__ __forceinline__ void gld16(const void* g, void* l) {
    __builtin_amdgcn_global_load_lds(
        (const __attribute__((address_space(1))) void*)g,
        (__attribute__((address_space(3))) void*)l, 16, 0, 0);
}
// swap lanes 0<->1, 2<->3 within each quad (DPP quad_perm(1,0,3,2))
__device__ __forceinline__ float dpp_swap1(float x) {
    return __builtin_bit_cast(float,
        __builtin_amdgcn_mov_dpp(__builtin_bit_cast(int, x), 0xB1, 0xF, 0xF, false));
}
// raw workgroup barrier without the __syncthreads() vmcnt(0) drain
__device__ __forceinline__ void rawbar() {
    __builtin_amdgcn_sched_barrier(0);
    __builtin_amdgcn_s_barrier();
    __builtin_amdgcn_sched_barrier(0);
}

// ---------------------------------------------------------------------------
// prep: fused fp32->fp16 casts (q,k,v,wq,wk,wv,wo) + mask bit-pack.
// grid (4096, 8), 256 thr.  y 0-2: qkv rows (R=4096); y 3-6: weights
// (R=1024, blocks >=1024 idle); y 7: mask_pack (16 words/block).
// ---------------------------------------------------------------------------
__global__ __launch_bounds__(256)
void prep(const float* __restrict__ q, const float* __restrict__ k,
          const float* __restrict__ v, const float* __restrict__ wq,
          const float* __restrict__ wk, const float* __restrict__ wv,
          const float* __restrict__ wo, const int* __restrict__ mask,
          _Float16* __restrict__ Ah, _Float16* __restrict__ Wh,
          unsigned long long* __restrict__ mb) {
    const int y = blockIdx.y;
    if (y < 7) {
        if (y >= 3 && blockIdx.x >= 1024) return;   // weights: R=1024
        const float* src = (y == 0) ? q : (y == 1) ? k : (y == 2) ? v :
                           (y == 3) ? wq : (y == 4) ? wk : (y == 5) ? wv : wo;
        _Float16* dst = (y < 3) ? (Ah + (size_t)y * M_ROWS * 1024)
                                : (Wh + (size_t)(y - 3) * 1024 * 1024);
        const size_t idx = ((size_t)blockIdx.x * 256 + threadIdx.x) * 4;
        float4 f = *(const float4*)&src[idx];
        half4v h = {(_Float16)f.x, (_Float16)f.y, (_Float16)f.z, (_Float16)f.w};
        *(half4v*)&dst[idx] = h;
    } else {
        const int wv_ = threadIdx.x >> 6, lane = threadIdx.x & 63;
#pragma unroll
        for (int i = 0; i < 4; i++) {
            const int gw = blockIdx.x * 16 + wv_ * 4 + i;
            const int row = gw >> 5, wid = gw & 31;
            const int mv = mask[(size_t)row * S_LEN + wid * 64 + lane];
            unsigned long long bal = __ballot(mv != 0);
            if (lane == 0) mb[gw] = bal;
        }
    }
}

// ---------------------------------------------------------------------------
// C = A[M,1024] @ W[1024,1024]^T (+bias), fp16 MFMA.  128x128 tile +
// chunked XCD swizzle (round-10 exact, best measured: each XCD owns 4m x 4n
// super-tiles of 16 blocks; working set 2 MB < 4 MB L2, both operands
// XCD-local).  Round-11 A/B closed the tile-size question: 128x64 loses
// ~14 us even with chunking (per-block loop overhead doubles).
// K-loop (validated round 6, issue-early/gate-late): vmcnt(0)+rawbar gate
// -> ds_read frags -> lgkmcnt(0)+rawbar -> issue tile k+1 -> MFMAs.
// OUTMODE 0: fp32 row-major out.  OUTMODE 1: fp16 head-major via
// LDS-staged coalesced epilogue; z==0 (Q) pre-scaled; z==2 (V) staged
// transposed -> lands directly in Vt [bh][d][s].
// ---------------------------------------------------------------------------
template <int OUTMODE>
__global__ __launch_bounds__(256)
void gemm_f16(const _Float16* __restrict__ Abase, const _Float16* __restrict__ Wbase,
              const float* __restrict__ b0, const float* __restrict__ b1,
              const float* __restrict__ b2, void* __restrict__ Obase,
              void* __restrict__ Obase2) {
    __shared__ __align__(16) _Float16 SM[16384];   // As | Ws ; reused by epilogue
    _Float16* As = SM;
    _Float16* Ws = SM + 8192;
    const int tid = threadIdx.x;
    const int w = tid >> 6, lane = tid & 63;
    const int l15 = lane & 15, q4 = lane >> 4;

    // chunked XCD swizzle: hardware xcd = linear_id % 8; one chunk = 16
    // blocks (4m x 4n) all with the same id%8, consecutive slots.
    const int id = blockIdx.x + (blockIdx.y << 3) +
                   ((OUTMODE == 1) ? ((int)blockIdx.z << 8) : 0);
    const int xcd = id & 7, slot = id >> 3;
    const int chunk = slot >> 4, t = slot & 15;
    const int g = chunk * 8 + xcd;          // global chunk index
    const int z = (OUTMODE == 1) ? (g >> 4) : 0;
    const int cz = g & 15;                  // chunk within z: 8 m-chunks x 2 n-chunks
    const int mi = (cz & 7) * 4 + (t >> 2);
    const int ni = (cz >> 3) * 4 + (t & 3);
    const int m0 = mi * 128, n0 = ni * 128;
    const int wm = w >> 1, wn = w & 1;

    const _Float16* A = Abase + (size_t)z * M_ROWS * 1024;
    const _Float16* W = Wbase + (size_t)z * 1024 * 1024;
    const float* bias = (OUTMODE == 1) ? ((z == 0) ? b0 : (z == 1) ? b1 : b2) : b0;

    int srow[4], sseg[4];
#pragma unroll
    for (int i = 0; i < 4; i++) {
        const int slot2 = i * 256 + tid;
        srow[i] = slot2 >> 3;
        sseg[i] = ((slot2 & 7) ^ (srow[i] & 7)) * 8;
    }

    int aoff[4][2], woff[4][2];
#pragma unroll
    for (int r = 0; r < 4; r++) {
        const int ar = wm * 64 + r * 16 + l15;
        const int wr = wn * 64 + r * 16 + l15;
#pragma unroll
        for (int kc = 0; kc < 2; kc++) {
            aoff[r][kc] = (ar * 8 + ((kc * 4 + q4) ^ (ar & 7))) * 8;
            woff[r][kc] = (wr * 8 + ((kc * 4 + q4) ^ (wr & 7))) * 8;
        }
    }

    floatx4 acc[4][4];
#pragma unroll
    for (int r = 0; r < 4; r++)
#pragma unroll
        for (int c = 0; c < 4; c++) acc[r][c] = (floatx4){0.f, 0.f, 0.f, 0.f};

    // prologue: stage tile k0=0
#pragma unroll
    for (int i = 0; i < 4; i++) {
        const int lb = (i * 256 + w * 64) * 8;
        gld16(&A[(size_t)(m0 + srow[i]) * 1024 + sseg[i]], &As[lb]);
        gld16(&W[(size_t)(n0 + srow[i]) * 1024 + sseg[i]], &Ws[lb]);
    }

    for (int k0 = 0; k0 < 1024; k0 += 64) {
        // gate: tile k0 landed (loads flew over previous MFMA block)
        __builtin_amdgcn_sched_barrier(0);
        asm volatile("s_waitcnt vmcnt(0)" ::: "memory");
        rawbar();

        half8 af[4][2], wf[4][2];
#pragma unroll
        for (int r = 0; r < 4; r++)
#pragma unroll
            for (int kc = 0; kc < 2; kc++) {
                af[r][kc] = ldh8(&As[aoff[r][kc]]);
                wf[r][kc] = ldh8(&Ws[woff[r][kc]]);
            }
        // all waves done reading the LDS tile -> safe to overwrite
        asm volatile("s_waitcnt lgkmcnt(0)" ::: "memory");
        rawbar();

        if (k0 < 1024 - 64) {
#pragma unroll
            for (int i = 0; i < 4; i++) {
                const int lb = (i * 256 + w * 64) * 8;
                gld16(&A[(size_t)(m0 + srow[i]) * 1024 + (k0 + 64) + sseg[i]], &As[lb]);
                gld16(&W[(size_t)(n0 + srow[i]) * 1024 + (k0 + 64) + sseg[i]], &Ws[lb]);
            }
        }
        __builtin_amdgcn_sched_barrier(0);   // keep stage-issue above the MFMAs

#pragma unroll
        for (int kc = 0; kc < 2; kc++)
#pragma unroll
            for (int r = 0; r < 4; r++)
#pragma unroll
                for (int c = 0; c < 4; c++)
                    acc[r][c] = __builtin_amdgcn_mfma_f32_16x16x32_f16(
                        af[r][kc], wf[c][kc], acc[r][c], 0, 0, 0);
    }

    if (OUTMODE == 0) {
#pragma unroll
        for (int r = 0; r < 4; r++)
#pragma unroll
            for (int c = 0; c < 4; c++) {
                const int n = n0 + wn * 64 + c * 16 + l15;
                const int mbase = m0 + wm * 64 + r * 16 + q4 * 4;
#pragma unroll
                for (int reg = 0; reg < 4; reg++)
                    ((float*)Obase)[(size_t)(mbase + reg) * 1024 + n] =
                        acc[r][c][reg] + bias[n];
            }
    } else {
        const int h0 = n0 >> 6;          // 2 heads per 128-n block column
        const int bB = m0 >> 11;         // batch (tile never crosses: 2048%128==0)
        if (z == 2) {
            // stage transposed E[n][m] (XOR-swizzled 16-B slots)
#pragma unroll
            for (int r = 0; r < 4; r++)
#pragma unroll
                for (int c = 0; c < 4; c++) {
                    const int nl = wn * 64 + c * 16 + l15;
                    const int ml = wm * 64 + r * 16 + q4 * 4;
                    half4v hv;
#pragma unroll
                    for (int reg = 0; reg < 4; reg++)
                        hv[reg] = (_Float16)(acc[r][c][reg] + bias[n0 + nl]);
                    const int seg = ml >> 3, wi = ml & 7;
                    *(half4v*)&SM[nl * 128 + ((seg ^ (nl & 7)) << 3) + wi] = hv;
                }
            __syncthreads();
#pragma unroll
            for (int it = 0; it < 8; it++) {
                const int chunk2 = it * 256 + tid;
                const int row = chunk2 >> 4, seg = chunk2 & 15;   // row=n, seg of m
                half8 v8 = ldh8(&SM[row * 128 + ((seg ^ (row & 7)) << 3)]);
                const int d = row & 63, hh = row >> 6;
                const int s = (m0 & 2047) + seg * 8;
                *(uint4*)&((_Float16*)Obase2)[
                    (((size_t)((bB * 16 + h0 + hh) * 64 + d)) << 11) + s] =
                    __builtin_bit_cast(uint4, v8);
            }
        } else {
            const float sc = (z == 0) ? 0.125f * LOG2E : 1.0f;
            // stage E[m][n] (scalar b16 writes, XOR-swizzled 16-B slots)
#pragma unroll
            for (int r = 0; r < 4; r++)
#pragma unroll
                for (int c = 0; c < 4; c++) {
                    const int nl = wn * 64 + c * 16 + l15;
                    const int seg = nl >> 3, wi = nl & 7;
                    const float bv = bias[n0 + nl];
#pragma unroll
                    for (int reg = 0; reg < 4; reg++) {
                        const int ml = wm * 64 + r * 16 + q4 * 4 + reg;
                        SM[ml * 128 + ((seg ^ (ml & 7)) << 3) + wi] =
                            (_Float16)((acc[r][c][reg] + bv) * sc);
                    }
                }
            __syncthreads();
            _Float16* Oz = (_Float16*)Obase + (size_t)z * M_ROWS * 1024;
#pragma unroll
            for (int it = 0; it < 8; it++) {
                const int chunk2 = it * 256 + tid;
                const int row = chunk2 >> 4, seg = chunk2 & 15;   // row=m, seg of n
                half8 v8 = ldh8(&SM[row * 128 + ((seg ^ (row & 7)) << 3)]);
                const int s = (m0 + row) & 2047;
                const int hh = seg >> 3, d = (seg & 7) * 8;
                *(uint4*)&Oz[(((size_t)((bB * 16 + h0 + hh)) * S_LEN + s) << 6) + d] =
                    __builtin_bit_cast(uint4, v8);
            }
        }
    }
}

// ---------------------------------------------------------------------------
// MFMA flash attention v10 = round-6 pipeline + bh-chunk XCD swizzle: grid
// (16,32) linearizes as id=x+16y, so the 16 q-blocks sharing one bh's K/V
// (512 KB) scattered across all 8 XCDs -> 8x L2 re-fetch (FETCH 74 MB vs
// 33 MB min) and HBM-latency gates.  Remap so each XCD owns 4 whole bh's
// (all 16 q-blocks): xcd=id&7, slot=id>>3, bh=xcd*4+(slot>>4), qx=slot&15.
// Bijective; whole grid co-resident (2 blocks/CU x 256 CU = 512) so the
// sharing is temporal as well as spatial.  Mechanism validated in round 10
// on the GEMMs.
// Grid (S/128, B*H), 512 thr, LDS 68.9 KB -> 2 blocks/CU = 16 waves/CU.
// ---------------------------------------------------------------------------
__global__ __launch_bounds__(512, 4)
void attn_mfma(const _Float16* __restrict__ Qh, const _Float16* __restrict__ Kh,
               const _Float16* __restrict__ Vt, const unsigned long long* __restrict__ mb,
               _Float16* __restrict__ Xh) {
    __shared__ __align__(16) _Float16 Ks[2][64 * 64];   // [half][key][d]  16 KB
    __shared__ __align__(16) _Float16 Vs[2][64 * 64];   // [half][d][key]  16 KB
    __shared__ __align__(16) _Float16 Ps[8][32 * 72];   // per-wave P, 36.9 KB

    const int tid = threadIdx.x;
    const int w = tid >> 6, lane = tid & 63;
    const int z = w >> 2, w4 = w & 3;       // key-half, wave-within-half
    const int t255 = tid & 255;
    const int l15 = lane & 15, q4 = lane >> 4;

    // bh-chunk XCD swizzle (see header comment)
    const int id = blockIdx.x + (blockIdx.y << 4);
    const int xcd = id & 7, slot = id >> 3;
    const int bh = xcd * 4 + (slot >> 4);
    const int qx = slot & 15;
    const int b = bh >> 4, h = bh & 15;
    const int qb = qx * 128 + w4 * 32;
    const int kbase = z * 1024;

    const _Float16* Qg = Qh + ((size_t)bh * S_LEN + qb) * DK;
    const _Float16* Kg = Kh + ((size_t)bh * S_LEN + kbase) * DK;
    const _Float16* Vg = Vt + (size_t)bh * DK * S_LEN + kbase;

    // Q fragments (A-operand), resident all kernel (scale pre-folded in gemm)
    half8 Aq[2][2];
#pragma unroll
    for (int qs = 0; qs < 2; qs++)
#pragma unroll
        for (int ch = 0; ch < 2; ch++)
            Aq[qs][ch] = ldh8(&Qg[(qs * 16 + l15) * DK + ch * 32 + q4 * 8]);

    // staging slots within each 256-thread half
    int grow[2], gseg[2];
#pragma unroll
    for (int i = 0; i < 2; i++) {
        const int s2 = i * 256 + t255;
        grow[i] = s2 >> 3;
        gseg[i] = ((s2 & 7) ^ (grow[i] & 7)) * 8;
    }

    // fragment base offsets (halfs) into swizzled Ks/Vs; full offset =
    // kb[ch] + jt*1024 (jt*1024 folds into the ds_read immediate)
    int kb[2];
#pragma unroll
    for (int ch = 0; ch < 2; ch++)
        kb[ch] = l15 * 64 + (((ch * 4 + q4) ^ (l15 & 7)) * 8);

    // mask word base: row (qb + q4*4), key-half offset folded in.
    // index per (qs,reg,jw) = qs*512 + reg*32 + jw
    const unsigned long long* mrow_p = mb + (size_t)(qb + q4 * 4) * (S_LEN / 64) + z * 16;

    floatx4 O[2][4];
#pragma unroll
    for (int qs = 0; qs < 2; qs++)
#pragma unroll
        for (int nt = 0; nt < 4; nt++) O[qs][nt] = (floatx4){0.f, 0.f, 0.f, 0.f};
    floatx4 lacc[2];
    lacc[0] = (floatx4){0.f, 0.f, 0.f, 0.f};
    lacc[1] = (floatx4){0.f, 0.f, 0.f, 0.f};

    half8 onesB;
#pragma unroll
    for (int i = 0; i < 8; i++) onesB[i] = (_Float16)1.0f;

    const bool evenlane = ((lane & 1) == 0);

    // prologue: stage K_0 then V_0   (FIFO: K,K,V,V)
#pragma unroll
    for (int i = 0; i < 2; i++) {
        const int lb = (i * 256 + w4 * 64) * 8;
        gld16(&Kg[(size_t)grow[i] * DK + gseg[i]], &Ks[z][lb]);
    }
#pragma unroll
    for (int i = 0; i < 2; i++) {
        const int lb = (i * 256 + w4 * 64) * 8;
        gld16(&Vg[(size_t)grow[i] * S_LEN + gseg[i]], &Vs[z][lb]);
    }

    for (int j0 = 0; j0 < 1024; j0 += 64) {
        const int jn = (j0 + 64) & 1023;   // wrap keeps vmcnt schedule uniform
        const int jw = j0 >> 6;

        // ---- K gate: my K_j landed (V_j may still fly); then block-wide ----
        __builtin_amdgcn_sched_barrier(0);
        asm volatile("s_waitcnt vmcnt(2)" ::: "memory");
        rawbar();

        // ---- QK + fused softmax (per-jt: only one floatx4 live) ----
#pragma unroll
        for (int qs = 0; qs < 2; qs++) {
            unsigned long long mw[4];
#pragma unroll
            for (int jt = 0; jt < 4; jt++) {
                floatx4 c = (floatx4){0.f, 0.f, 0.f, 0.f};
                __builtin_amdgcn_s_setprio(1);
                c = __builtin_amdgcn_mfma_f32_16x16x32_f16(
                    Aq[qs][0], ldh8(&Ks[z][jt * 1024 + kb[0]]), c, 0, 0, 0);
                c = __builtin_amdgcn_mfma_f32_16x16x32_f16(
                    Aq[qs][1], ldh8(&Ks[z][jt * 1024 + kb[1]]), c, 0, 0, 0);
                __builtin_amdgcn_s_setprio(0);
                if (jt == 0) {
#pragma unroll
                    for (int reg = 0; reg < 4; reg++)
                        mw[reg] = mrow_p[qs * 512 + reg * 32 + jw];
                }
#pragma unroll
                for (int reg = 0; reg < 4; reg++) {
                    const unsigned ttw =
                        (unsigned)(mw[reg] >> (jt >= 2 ? 32 : 0)) >> l15;
                    const unsigned sel = ttw & (1u << ((jt & 1) * 16));
                    float p = __builtin_amdgcn_exp2f(c[reg]);
                    p = sel ? p : EXPM1;
                    const float po = dpp_swap1(p);
                    if (evenlane) {
                        *(unsigned*)&Ps[w][(qs * 16 + q4 * 4 + reg) * 72 +
                                           jt * 16 + l15] =
                            __builtin_bit_cast(unsigned,
                                __builtin_amdgcn_cvt_pkrtz(p, po));
                    }
                }
            }
        }

        // ---- Ks consumed block-wide -> prefetch K_{j+1} (flies over PV) ----
        rawbar();
#pragma unroll
        for (int i = 0; i < 2; i++) {
            const int lb = (i * 256 + w4 * 64) * 8;
            gld16(&Kg[(size_t)(jn + grow[i]) * DK + gseg[i]], &Ks[z][lb]);
        }

        // ---- V gate: my V_j landed (K_{j+1} in flight); block-wide ----
        __builtin_amdgcn_sched_barrier(0);
        asm volatile("s_waitcnt vmcnt(2)" ::: "memory");
        rawbar();

        // ---- PV: O[qs] += P[qs] @ V ; Σp via all-ones B ----
#pragma unroll
        for (int qs = 0; qs < 2; qs++) {
            half8 Ap[2];
#pragma unroll
            for (int ch = 0; ch < 2; ch++)
                Ap[ch] = ldh8(&Ps[w][(qs * 16 + l15) * 72 + ch * 32 + q4 * 8]);
            __builtin_amdgcn_s_setprio(1);
            lacc[qs] = __builtin_amdgcn_mfma_f32_16x16x32_f16(Ap[0], onesB, lacc[qs], 0, 0, 0);
            lacc[qs] = __builtin_amdgcn_mfma_f32_16x16x32_f16(Ap[1], onesB, lacc[qs], 0, 0, 0);
#pragma unroll
            for (int nt = 0; nt < 4; nt++) {
                O[qs][nt] = __builtin_amdgcn_mfma_f32_16x16x32_f16(
                    Ap[0], ldh8(&Vs[z][nt * 1024 + kb[0]]), O[qs][nt], 0, 0, 0);
                O[qs][nt] = __builtin_amdgcn_mfma_f32_16x16x32_f16(
                    Ap[1], ldh8(&Vs[z][nt * 1024 + kb[1]]), O[qs][nt], 0, 0, 0);
            }
            __builtin_amdgcn_s_setprio(0);
        }

        // ---- Vs consumed block-wide -> prefetch V_{j+1} (flies over QK) ----
        rawbar();
#pragma unroll
        for (int i = 0; i < 2; i++) {
            const int lb = (i * 256 + w4 * 64) * 8;
            gld16(&Vg[(size_t)grow[i] * S_LEN + jn + gseg[i]], &Vs[z][lb]);
        }
    }
    __builtin_amdgcn_sched_barrier(0);

    // cross-half combine via LDS (reuse Ps region: all P reads are done;
    // the loop's final rawbar ordered the last PV reads before these writes)
    float* Obuf = (float*)&Ps[0][0];                  // [4][32][65] fp32, 33.3 KB
    if (z == 1) {
#pragma unroll
        for (int qs = 0; qs < 2; qs++)
#pragma unroll
            for (int reg = 0; reg < 4; reg++) {
                const int rl = w4 * 32 + qs * 16 + q4 * 4 + reg;
#pragma unroll
                for (int nt = 0; nt < 4; nt++)
                    Obuf[rl * 65 + nt * 16 + l15] = O[qs][nt][reg];
                if (l15 == 0) Obuf[rl * 65 + 64] = lacc[qs][reg];
            }
    }
    __syncthreads();
    if (z == 0) {
#pragma unroll
        for (int qs = 0; qs < 2; qs++)
#pragma unroll
            for (int reg = 0; reg < 4; reg++) {
                const int rl = w4 * 32 + qs * 16 + q4 * 4 + reg;
                const float inv = 1.0f / (lacc[qs][reg] + Obuf[rl * 65 + 64]);
                const int srow = qb + qs * 16 + q4 * 4 + reg;
                _Float16* Xrow = Xh + (size_t)(b * S_LEN + srow) * 1024 + h * DK;
#pragma unroll
                for (int nt = 0; nt < 4; nt++)
                    Xrow[nt * 16 + l15] =
                        (_Float16)((O[qs][nt][reg] + Obuf[rl * 65 + nt * 16 + l15]) * inv);
            }
    }
}

// ---------------------------------------------------------------------------
extern "C" void kernel_launch(void* const* d_in, const int* in_sizes, int n_in,
                              void* d_out, int out_size, void* d_ws, size_t ws_size,
                              hipStream_t stream) {
    const float* q  = (const float*)d_in[0];
    const float* k  = (const float*)d_in[1];
    const float* v  = (const float*)d_in[2];
    const int* mask = (const int*)d_in[3];
    const float* wq = (const float*)d_in[4];
    const float* bq = (const float*)d_in[5];
    const float* wk = (const float*)d_in[6];
    const float* bk = (const float*)d_in[7];
    const float* wv = (const float*)d_in[8];
    const float* bv = (const float*)d_in[9];
    const float* wo = (const float*)d_in[10];
    const float* bo = (const float*)d_in[11];
    float* out = (float*)d_out;

    char* ws = (char*)d_ws;
    const size_t MB = 1u << 20;
    _Float16* Wh   = (_Float16*)ws;                    // 4 x 2 MB (wq,wk,wv,wo)
    _Float16* Ah   = (_Float16*)(ws + 8 * MB);         // 3 x 8 MB (q,k,v fp16)
    _Float16* QKVh = (_Float16*)(ws + 32 * MB);        // 2 x 8 MB head-major (Q,K)
    _Float16* Vt   = (_Float16*)(ws + 56 * MB);        // 8 MB
    unsigned long long* mb = (unsigned long long*)(ws + 64 * MB);  // 512 KB
    _Float16* Xh   = Ah;                               // reuse q slot (8 MB)

    prep<<<dim3(4096, 8), 256, 0, stream>>>(q, k, v, wq, wk, wv, wo, mask,
                                            Ah, Wh, mb);

    gemm_f16<1><<<dim3(8, 32, 3), 256, 0, stream>>>(Ah, Wh, bq, bk, bv, QKVh, Vt);

    attn_mfma<<<dim3(16, 32), 512, 0, stream>>>(QKVh, QKVh + (size_t)M_ROWS * 1024,
                                                Vt, mb, Xh);

    gemm_f16<0><<<dim3(8, 32), 256, 0, stream>>>(Xh, Wh + (size_t)3 * 1024 * 1024,
                                                 bo, bo, bo, out, nullptr);
}